// Round 2
// baseline (17439.413 us; speedup 1.0000x reference)
//
#include <hip/hip_runtime.h>

#define NWG   256
#define TPB   256
#define Bsz   128
#define Tlen  512
#define Pn    10
#define In    50
#define Hn    512
#define Cn    8
#define KTOT  562          // 512 (h) + 50 (emb)
#define KPAD  564          // padded to 141 float4
#define KC4   141
#define BSL   32           // batch rows per group
#define GRPW  64           // j-WGs per batch group

// ---- workspace layout (floats) ----
#define OFF_BAR 0                      // 4 groups x 128 floats; 64 arrival flags each
#define OFF_H   1024
#define HBUF_N  (2*Bsz*Hn)
#define OFF_S   (OFF_H + HBUF_N)
#define SROW    12                     // padded score row (10 used)
#define SBUF_N  (3*Bsz*SROW)
#define WS_FLOATS (OFF_S + SBUF_N)

// ---- LDS layout (floats) ----
#define L_SW    0                      // [32][KPAD] gate rows: [W_hh | W_ih | 0,0]
#define L_SH    (32*KPAD)              // [32][KPAD] [h(512) | emb(50) | 0,0]
#define L_SWA   (L_SH + 32*KPAD)       // [8][52] Wa rows of my j-slice, col 50 = ba
#define L_BIAS  (L_SWA + 8*52)         // [32]
#define L_GATES (L_BIAS + 32)          // [32][33]
#define L_ATTN  (L_GATES + 32*33)      // [32][12]
#define L_HNEW  (L_ATTN + 32*12)       // [32][8]
#define L_PROJX (L_HNEW + 32*8)        // [320][8]  proj-x for next step
#define LDS_FLOATS (L_PROJX + 320*8)   // 40800 floats = 163200 B (<= 160 KiB)
#define LDS_BYTES  (LDS_FLOATS*4)

// Per-group flag barrier: each WG's tid0 release-stores its flag; wave 0 of every
// WG polls all 64 flags (coalesced, one cacheline region). Fence discipline
// identical to the R1-proven pattern (threadfence release before store,
// threadfence acquire after observation, bracketed by __syncthreads).
__device__ inline void groupBarrier(unsigned* flags, int jw, unsigned target) {
  __syncthreads();
  if (threadIdx.x < GRPW) {
    if (threadIdx.x == 0) {
      __threadfence();                 // release: flush this WG's writes
      __hip_atomic_store(&flags[jw], target, __ATOMIC_RELEASE, __HIP_MEMORY_SCOPE_AGENT);
    }
    while (__hip_atomic_load(&flags[threadIdx.x], __ATOMIC_RELAXED,
                             __HIP_MEMORY_SCOPE_AGENT) < target) {
      __builtin_amdgcn_s_sleep(1);
    }
  }
  if (threadIdx.x == 0) __threadfence();   // acquire: invalidate stale caches
  __syncthreads();
}

extern "C" __global__ void __launch_bounds__(TPB, 1) fused_att_lstm(
    const float* __restrict__ x,   const float* __restrict__ mask,
    const float* __restrict__ Wa,  const float* __restrict__ ba,
    const float* __restrict__ Wih, const float* __restrict__ Whh,
    const float* __restrict__ bih, const float* __restrict__ bhh,
    const float* __restrict__ Wfc, const float* __restrict__ bfc,
    float* __restrict__ out, float* __restrict__ ws)
{
  extern __shared__ __align__(16) float lds[];
  float* sW     = lds + L_SW;
  float* sH     = lds + L_SH;
  float* sWa    = lds + L_SWA;
  float* sBias  = lds + L_BIAS;
  float* sGates = lds + L_GATES;
  float* sAttn  = lds + L_ATTN;
  float* sHnew  = lds + L_HNEW;
  float* sProjX = lds + L_PROJX;

  const int tid = threadIdx.x;
  const int wg  = blockIdx.x;
  const int jw  = wg & 63;         // j-slice within group (8 hidden dims)
  const int grp = wg >> 6;         // batch group (32 batches)
  const int bG0 = grp * BSL;
  const int jG0 = jw * 8;

  unsigned* flags = reinterpret_cast<unsigned*>(ws) + grp * 128;
  float* hbuf = ws + OFF_H;        // [2][B][H]
  float* Sbuf = ws + OFF_S;        // [3][B][SROW]

  // ---- load resident weights into LDS ----
  for (int idx = tid; idx < 32*KPAD; idx += TPB) {
    int r = idx / KPAD, k = idx - r*KPAD;
    int jj = r >> 2, g = r & 3;
    int grow = g*Hn + jG0 + jj;    // torch gate order i,f,g,o
    float v = 0.f;
    if (k < Hn)        v = Whh[grow*Hn + k];
    else if (k < KTOT) v = Wih[grow*In + (k - Hn)];
    sW[idx] = v;
  }
  for (int idx = tid; idx < 8*52; idx += TPB) {
    int jj = idx / 52, i = idx - jj*52;
    float v = 0.f;
    if (i < In)       v = Wa[(jG0+jj)*In + i];
    else if (i == In) v = ba[jG0+jj];
    sWa[idx] = v;
  }
  if (tid < 32) {
    int jj = tid >> 2, g = tid & 3;
    int grow = g*Hn + jG0 + jj;
    sBias[tid] = bih[grow] + bhh[grow];
  }
  if (tid < 32) { sH[tid*KPAD + 562] = 0.f; sH[tid*KPAD + 563] = 0.f; }
  __syncthreads();

  const int lb = tid >> 3, ljj = tid & 7;   // LSTM map: (b, jj)
  const int tx = tid & 15, ty = tid >> 4;   // GEMM map
  float c_reg = 0.f;
  unsigned bgen = 0;

  for (int t = 0; t < Tlen; ++t) {
    const float* hprev = hbuf + ((t+1)&1)*Bsz*Hn;
    float*       hcur  = hbuf + (t&1)*Bsz*Hn;
    const float* Scur  = Sbuf + (t%3)*Bsz*SROW;
    float*       Snext = Sbuf + ((t+1)%3)*Bsz*SROW;
    float*       Szero = Sbuf + ((t+2)%3)*Bsz*SROW;

    // ---- A: stage h (issue loads first), zero future score slice, softmax ----
    {
      const float4* src  = reinterpret_cast<const float4*>(hprev) + bG0*(Hn/4);
      float4*       dst4 = reinterpret_cast<float4*>(sH);
      #pragma unroll
      for (int it = 0; it < 16; ++it) {
        int f = it*TPB + tid;             // 0..4095
        int b = f >> 7, kf = f & 127;
        dst4[b*KC4 + kf] = src[b*(Hn/4) + kf];
      }
    }
    if (tid < 6) Szero[bG0*SROW + jw*6 + tid] = 0.f;   // 64 WGs x 6 = 384 floats

    if (tid < BSL) {
      int bG = bG0 + tid;
      const float* srow = Scur + bG*SROW;
      const float* mrow = mask + ((size_t)bG*Tlen + t)*Pn*In;
      float sc[Pn]; float mx = -1e30f;
      #pragma unroll
      for (int p = 0; p < Pn; ++p) {
        float s = srow[p];
        s = (mrow[p*In] > 0.f) ? s : -1e9f;
        sc[p] = s; mx = fmaxf(mx, s);
      }
      float den = 0.f;
      #pragma unroll
      for (int p = 0; p < Pn; ++p) { sc[p] = expf(sc[p] - mx); den += sc[p]; }
      float inv = 1.f / den;
      #pragma unroll
      for (int p = 0; p < Pn; ++p) sAttn[tid*12 + p] = sc[p] * inv;
    }
    __syncthreads();

    // ---- B: emb (this step) + proj-x (next step), both x-reads overlap ----
    for (int idx = tid; idx < BSL*In; idx += TPB) {
      int b = idx / In, i = idx - b*In;
      const float* xb = x + (((size_t)(bG0+b)*Tlen + t)*Pn)*In + i;
      float e = 0.f;
      #pragma unroll
      for (int p = 0; p < Pn; ++p) e = fmaf(sAttn[b*12+p], xb[p*In], e);
      sH[b*KPAD + Hn + i] = e;
    }
    if (t < Tlen-1) {
      for (int pr = tid; pr < BSL*Pn; pr += TPB) {
        int b = pr / Pn, p = pr - b*Pn;
        const float* xrow = x + (((size_t)(bG0+b)*Tlen + (t+1))*Pn + p)*In;
        float a0 = sWa[0*52+50], a1 = sWa[1*52+50], a2 = sWa[2*52+50], a3 = sWa[3*52+50];
        float a4 = sWa[4*52+50], a5 = sWa[5*52+50], a6 = sWa[6*52+50], a7 = sWa[7*52+50];
        #pragma unroll 10
        for (int i = 0; i < In; ++i) {
          float xv = xrow[i];
          a0 = fmaf(sWa[0*52+i], xv, a0); a1 = fmaf(sWa[1*52+i], xv, a1);
          a2 = fmaf(sWa[2*52+i], xv, a2); a3 = fmaf(sWa[3*52+i], xv, a3);
          a4 = fmaf(sWa[4*52+i], xv, a4); a5 = fmaf(sWa[5*52+i], xv, a5);
          a6 = fmaf(sWa[6*52+i], xv, a6); a7 = fmaf(sWa[7*52+i], xv, a7);
        }
        float* dst = sProjX + pr*8;
        dst[0]=a0; dst[1]=a1; dst[2]=a2; dst[3]=a3;
        dst[4]=a4; dst[5]=a5; dst[6]=a6; dst[7]=a7;
      }
    }
    __syncthreads();

    // ---- C: gate GEMM 32b x 32r, k=564; 2b x 2r per thread ----
    {
      const float4* hA = reinterpret_cast<const float4*>(sH) + ty*KC4;
      const float4* hB = reinterpret_cast<const float4*>(sH) + (ty+16)*KC4;
      const float4* wA = reinterpret_cast<const float4*>(sW) + tx*KC4;
      const float4* wB = reinterpret_cast<const float4*>(sW) + (tx+16)*KC4;
      float a00a=0,a00b=0,a01a=0,a01b=0,a10a=0,a10b=0,a11a=0,a11b=0;
      #pragma unroll 3
      for (int kc = 0; kc < KC4; ++kc) {
        float4 h0 = hA[kc], h1 = hB[kc], w0 = wA[kc], w1 = wB[kc];
        a00a = fmaf(h0.x, w0.x, a00a); a00b = fmaf(h0.y, w0.y, a00b);
        a00a = fmaf(h0.z, w0.z, a00a); a00b = fmaf(h0.w, w0.w, a00b);
        a01a = fmaf(h0.x, w1.x, a01a); a01b = fmaf(h0.y, w1.y, a01b);
        a01a = fmaf(h0.z, w1.z, a01a); a01b = fmaf(h0.w, w1.w, a01b);
        a10a = fmaf(h1.x, w0.x, a10a); a10b = fmaf(h1.y, w0.y, a10b);
        a10a = fmaf(h1.z, w0.z, a10a); a10b = fmaf(h1.w, w0.w, a10b);
        a11a = fmaf(h1.x, w1.x, a11a); a11b = fmaf(h1.y, w1.y, a11b);
        a11a = fmaf(h1.z, w1.z, a11a); a11b = fmaf(h1.w, w1.w, a11b);
      }
      sGates[ty*33 + tx]           = a00a + a00b + sBias[tx];
      sGates[ty*33 + tx + 16]      = a01a + a01b + sBias[tx+16];
      sGates[(ty+16)*33 + tx]      = a10a + a10b + sBias[tx];
      sGates[(ty+16)*33 + tx + 16] = a11a + a11b + sBias[tx+16];
    }
    __syncthreads();

    // ---- D: LSTM pointwise; c in register ----
    {
      float gi = sGates[lb*33 + ljj*4 + 0];
      float gf = sGates[lb*33 + ljj*4 + 1];
      float gg = sGates[lb*33 + ljj*4 + 2];
      float go = sGates[lb*33 + ljj*4 + 3];
      float ig = 1.f/(1.f + expf(-gi));
      float fg = 1.f/(1.f + expf(-gf));
      float gc = tanhf(gg);
      float og = 1.f/(1.f + expf(-go));
      c_reg = fg*c_reg + ig*gc;
      float hn = og * tanhf(c_reg);
      hcur[(size_t)(bG0+lb)*Hn + jG0 + ljj] = hn;
      sHnew[lb*8 + ljj] = hn;
    }
    __syncthreads();

    // ---- E: partial scores for next step: 8-FMA dot + 320 atomics/WG ----
    if (t < Tlen-1) {
      for (int pr = tid; pr < BSL*Pn; pr += TPB) {
        int b = pr / Pn, p = pr - b*Pn;
        const float* hv = sHnew + b*8;
        const float* pv = sProjX + pr*8;
        float s = 0.f;
        #pragma unroll
        for (int jj = 0; jj < 8; ++jj) s = fmaf(hv[jj], pv[jj], s);
        atomicAdd(&Snext[(size_t)(bG0+b)*SROW + p], s);
      }
    }

    groupBarrier(flags, jw, ++bgen);
  }

  // ---- final classifier (jw==0 WG of each group) ----
  if (jw == 0) {
    const float* hfin = hbuf + ((Tlen-1)&1)*Bsz*Hn;
    int b = tid >> 3, cc = tid & 7;
    int bG = bG0 + b;
    const float4* hv = reinterpret_cast<const float4*>(hfin + (size_t)bG*Hn);
    const float4* wv = reinterpret_cast<const float4*>(Wfc + cc*Hn);
    float s0=0,s1=0,s2=0,s3=0;
    #pragma unroll 4
    for (int k = 0; k < Hn/4; ++k) {
      float4 a = hv[k], w = wv[k];
      s0 = fmaf(a.x,w.x,s0); s1 = fmaf(a.y,w.y,s1);
      s2 = fmaf(a.z,w.z,s2); s3 = fmaf(a.w,w.w,s3);
    }
    out[bG*Cn + cc] = (s0+s1)+(s2+s3) + bfc[cc];
  }
}

extern "C" void kernel_launch(void* const* d_in, const int* in_sizes, int n_in,
                              void* d_out, int out_size, void* d_ws, size_t ws_size,
                              hipStream_t stream) {
  const float* x    = (const float*)d_in[0];
  const float* mask = (const float*)d_in[1];
  const float* Wa   = (const float*)d_in[2];
  const float* ba   = (const float*)d_in[3];
  const float* Wih  = (const float*)d_in[4];
  const float* Whh  = (const float*)d_in[5];
  const float* bih  = (const float*)d_in[6];
  const float* bhh  = (const float*)d_in[7];
  const float* Wfc  = (const float*)d_in[8];
  const float* bfc  = (const float*)d_in[9];
  float* out = (float*)d_out;
  float* ws  = (float*)d_ws;

  // reset barrier flags + h/score buffers every launch (deterministic replay)
  hipMemsetAsync(d_ws, 0, (size_t)WS_FLOATS * sizeof(float), stream);

  (void)hipFuncSetAttribute((const void*)fused_att_lstm,
                            hipFuncAttributeMaxDynamicSharedMemorySize, LDS_BYTES);

  void* args[] = { (void*)&x, (void*)&mask, (void*)&Wa, (void*)&ba,
                   (void*)&Wih, (void*)&Whh, (void*)&bih, (void*)&bhh,
                   (void*)&Wfc, (void*)&bfc, (void*)&out, (void*)&ws };
  hipLaunchCooperativeKernel((void*)fused_att_lstm, dim3(NWG), dim3(TPB),
                             args, LDS_BYTES, stream);
}

// Round 3
// 13181.012 us; speedup vs baseline: 1.3231x; 1.3231x over previous
//
#include <hip/hip_runtime.h>

#define NWG   256
#define TPB   256
#define Bsz   128
#define Tlen  512
#define Pn    10
#define In    50
#define Hn    512
#define Cn    8
#define KTOT  562          // 512 (h) + 50 (emb)
#define KPAD  576          // padded; 144 float4 (multiple of 8 for XOR swizzle)
#define KF4   144
#define BSL   32           // batch rows per group
#define GRPW  64           // j-WGs per batch group

// ---- workspace layout (floats) ----
#define OFF_H   1024                   // [0..1023]: per-group barrier cnt/gen
#define HBUF_N  (2*Bsz*Hn)
#define OFF_S   (OFF_H + HBUF_N)
#define SROW    12
#define SBUF_N  (3*Bsz*SROW)
#define WS_FLOATS (OFF_S + SBUF_N)

// ---- LDS layout (floats) ----
#define L_SW     0                     // [32][KPAD] gate rows (swizzled)
#define L_SH     (32*KPAD)             // [32][KPAD] [h | emb | pad] (swizzled)
#define L_SCR    (2*32*KPAD)           // 3072: attn[32*10] | partialsT[3*16*64] | u[32*51]
#define L_SWA    (L_SCR + 3072)        // [8][51], col 50 = ba
#define L_BIAS   (L_SWA + 408)         // [32]
#define L_HNEW   (L_BIAS + 32)         // [8][33]  hnew[jj][b]
#define LDS_FLOATS (L_HNEW + 264)      // 40640 floats = 162560 B
#define LDS_BYTES  (LDS_FLOATS*4)

// per-group counter barrier (R1-proven fence discipline, scoped to 64 WGs)
__device__ inline void groupBarrier(unsigned* cnt, unsigned* gen, unsigned target) {
  __syncthreads();
  if (threadIdx.x == 0) {
    __threadfence();                       // release
    unsigned old = atomicAdd(cnt, 1u);
    if (old == target * (unsigned)GRPW - 1u) {
      __hip_atomic_store(gen, target, __ATOMIC_RELEASE, __HIP_MEMORY_SCOPE_AGENT);
    } else {
      while (__hip_atomic_load(gen, __ATOMIC_RELAXED, __HIP_MEMORY_SCOPE_AGENT) < target) {
        __builtin_amdgcn_s_sleep(2);
      }
    }
    __threadfence();                       // acquire
  }
  __syncthreads();
}

extern "C" __global__ void __launch_bounds__(TPB, 1) fused_att_lstm(
    const float* __restrict__ x,   const float* __restrict__ mask,
    const float* __restrict__ Wa,  const float* __restrict__ ba,
    const float* __restrict__ Wih, const float* __restrict__ Whh,
    const float* __restrict__ bih, const float* __restrict__ bhh,
    const float* __restrict__ Wfc, const float* __restrict__ bfc,
    float* __restrict__ out, float* __restrict__ ws)
{
  extern __shared__ __align__(16) float lds[];
  float* sW    = lds + L_SW;
  float* sH    = lds + L_SH;
  float* sScr  = lds + L_SCR;    // attn / partialsT / u (disjoint lifetimes)
  float* sWa   = lds + L_SWA;
  float* sBias = lds + L_BIAS;
  float* sHnew = lds + L_HNEW;

  const int tid = threadIdx.x;
  const int wg  = blockIdx.x;
  const int jw  = wg & 63;
  const int grp = wg >> 6;
  const int bG0 = grp * BSL;
  const int jG0 = jw * 8;

  unsigned* cnt = reinterpret_cast<unsigned*>(ws) + grp*64;
  unsigned* gen = cnt + 16;
  float* hbuf = ws + OFF_H;        // [2][B][H]
  float* Sbuf = ws + OFF_S;        // [3][B][SROW]

  // ---- load resident weights (swizzled store: f4idx ^= (row>>2)&7) ----
  for (int idx = tid; idx < 32*KPAD; idx += TPB) {
    int r = idx / KPAD, k = idx - r*KPAD;
    int jj = r >> 2, g = r & 3;
    int grow = g*Hn + jG0 + jj;    // torch gate order i,f,g,o
    float v = 0.f;
    if (k < Hn)        v = Whh[grow*Hn + k];
    else if (k < KTOT) v = Wih[grow*In + (k - Hn)];
    sW[r*KPAD + (((((k>>2) ^ ((r>>2)&7))) << 2) | (k & 3))] = v;
  }
  for (int idx = tid; idx < 8*51; idx += TPB) {
    int jj = idx / 51, i = idx - jj*51;
    sWa[idx] = (i < In) ? Wa[(jG0+jj)*In + i] : ba[jG0+jj];
  }
  if (tid < 32) {
    int jj = tid >> 2, g = tid & 3;
    int grow = g*Hn + jG0 + jj;
    sBias[tid] = bih[grow] + bhh[grow];
  }
  if (tid < 32) {                          // zero pad cols 562..575 of sH once
    for (int k = KTOT; k < KPAD; ++k)
      sH[tid*KPAD + (((((k>>2) ^ ((tid>>2)&7))) << 2) | (k & 3))] = 0.f;
  }
  __syncthreads();

  const int kg = tid >> 6;                 // k-split group (wave index)
  const int tb = (tid >> 3) & 7;           // batch-tile (4 rows: 4tb..4tb+3)
  const int tr = tid & 7;                  // gate-row tile (rows 4tr..4tr+3 = jj=tr)
  const int lane = tid & 63;
  float cr[4] = {0.f, 0.f, 0.f, 0.f};      // cell state (kg0 threads: 4 cells)
  unsigned bgen = 0;

  for (int t = 0; t < Tlen; ++t) {
    const float* hprev = hbuf + ((t+1)&1)*Bsz*Hn;
    float*       hcur  = hbuf + (t&1)*Bsz*Hn;
    const float* Scur  = Sbuf + (t%3)*Bsz*SROW;
    float*       Snext = Sbuf + ((t+1)%3)*Bsz*SROW;
    float*       Szero = Sbuf + ((t+2)%3)*Bsz*SROW;

    // ---- A: stage h (swizzled), zero future score slice, softmax ----
    {
      const float4* src = reinterpret_cast<const float4*>(hprev) + (size_t)bG0*(Hn/4);
      float4* dst = reinterpret_cast<float4*>(sH);
      #pragma unroll
      for (int it = 0; it < 16; ++it) {
        int f = it*TPB + tid;
        int b = f >> 7, kf = f & 127;
        dst[b*KF4 + (kf ^ ((b>>2)&7))] = src[b*(Hn/4) + kf];
      }
    }
    if (tid < 6) Szero[bG0*SROW + jw*6 + tid] = 0.f;

    if (tid < BSL) {
      int bG = bG0 + tid;
      const float* srow = Scur + (size_t)bG*SROW;
      const float* mrow = mask + ((size_t)bG*Tlen + t)*Pn*In;
      float sc[Pn]; float mx = -1e30f;
      #pragma unroll
      for (int p = 0; p < Pn; ++p) {
        float s = srow[p];
        s = (mrow[p*In] > 0.f) ? s : -1e9f;
        sc[p] = s; mx = fmaxf(mx, s);
      }
      float den = 0.f;
      #pragma unroll
      for (int p = 0; p < Pn; ++p) { sc[p] = expf(sc[p] - mx); den += sc[p]; }
      float inv = 1.f / den;
      #pragma unroll
      for (int p = 0; p < Pn; ++p) sScr[tid*10 + p] = sc[p] * inv;  // attn
    }
    __syncthreads();

    // ---- B: emb[b,i] -> sH cols 512..561 (swizzled scalar store) ----
    for (int idx = tid; idx < BSL*In; idx += TPB) {
      int b = idx / In, ic = idx - b*In;
      const float* xb = x + (((size_t)(bG0+b)*Tlen + t)*Pn)*In + ic;
      float e = 0.f;
      #pragma unroll
      for (int p = 0; p < Pn; ++p) e = fmaf(sScr[b*10+p], xb[p*In], e);
      int k = Hn + ic;
      sH[b*KPAD + (((((k>>2) ^ ((b>>2)&7))) << 2) | (k & 3))] = e;
    }
    __syncthreads();

    // ---- C: gate GEMM 32x32, 4-way k-split, 4x4 tiles, conflict-free ----
    float acc[4][4];
    {
      #pragma unroll
      for (int i = 0; i < 4; ++i)
        #pragma unroll
        for (int j = 0; j < 4; ++j) acc[i][j] = 0.f;
      const float4* sH4 = reinterpret_cast<const float4*>(sH);
      const float4* sW4 = reinterpret_cast<const float4*>(sW);
      const int kbeg = kg*36, kend = kbeg + 36;
      for (int kc = kbeg; kc < kend; ++kc) {
        float4 hv[4], wv[4];
        #pragma unroll
        for (int i = 0; i < 4; ++i) hv[i] = sH4[(4*tb+i)*KF4 + (kc ^ tb)];
        #pragma unroll
        for (int j = 0; j < 4; ++j) wv[j] = sW4[(4*tr+j)*KF4 + (kc ^ tr)];
        #pragma unroll
        for (int i = 0; i < 4; ++i)
          #pragma unroll
          for (int j = 0; j < 4; ++j) {
            acc[i][j] = fmaf(hv[i].x, wv[j].x, acc[i][j]);
            acc[i][j] = fmaf(hv[i].y, wv[j].y, acc[i][j]);
            acc[i][j] = fmaf(hv[i].z, wv[j].z, acc[i][j]);
            acc[i][j] = fmaf(hv[i].w, wv[j].w, acc[i][j]);
          }
      }
      if (kg > 0) {                        // transposed partials: stride-4B lanes
        float* dst = sScr + (kg-1)*1024 + lane;
        #pragma unroll
        for (int q = 0; q < 16; ++q) dst[q*64] = acc[q>>2][q&3];
      }
    }
    __syncthreads();

    // ---- D: kg0 reduces partials + LSTM cells (c in registers) ----
    if (kg == 0) {
      #pragma unroll
      for (int i = 0; i < 4; ++i) {
        float gv[4];
        #pragma unroll
        for (int g = 0; g < 4; ++g) {
          int q = i*4 + g;
          float v = acc[i][g];
          v += sScr[0*1024 + q*64 + lane];
          v += sScr[1*1024 + q*64 + lane];
          v += sScr[2*1024 + q*64 + lane];
          gv[g] = v + sBias[4*tr + g];
        }
        float ig = 1.f/(1.f + expf(-gv[0]));
        float fg = 1.f/(1.f + expf(-gv[1]));
        float gc = tanhf(gv[2]);
        float og = 1.f/(1.f + expf(-gv[3]));
        cr[i] = fg*cr[i] + ig*gc;
        float hn = og * tanhf(cr[i]);
        int b = 4*tb + i;
        sHnew[tr*33 + b] = hn;
        hcur[(size_t)(bG0+b)*Hn + jG0 + tr] = hn;
      }
    }
    __syncthreads();

    // ---- E1: partial u[b,i] = sum_jj Wa[jj,i]*hnew[b,jj]  (col 50 = ba.h) ----
    if (t < Tlen-1) {
      for (int idx = tid; idx < BSL*51; idx += TPB) {
        int b = idx / 51, ic = idx - b*51;
        float v = 0.f;
        #pragma unroll
        for (int jj = 0; jj < 8; ++jj) v = fmaf(sWa[jj*51+ic], sHnew[jj*33+b], v);
        sScr[idx] = v;                     // u overlays partials (lifetime ok)
      }
    }
    __syncthreads();

    // ---- E2: partial scores s[b,p] = u50 + x_{t+1}.u ; 320 atomics/WG ----
    if (t < Tlen-1) {
      for (int pr = tid; pr < BSL*Pn; pr += TPB) {
        int b = pr / Pn, p = pr - b*Pn;
        const float2* xp = reinterpret_cast<const float2*>(
            x + (((size_t)(bG0+b)*Tlen + (t+1))*Pn + p)*In);
        const float* u = sScr + b*51;
        float s = u[50];
        #pragma unroll
        for (int k2 = 0; k2 < 25; ++k2) {
          float2 xv = xp[k2];
          s = fmaf(xv.x, u[2*k2],   s);
          s = fmaf(xv.y, u[2*k2+1], s);
        }
        atomicAdd(&Snext[(size_t)(bG0+b)*SROW + p], s);
      }
    }

    groupBarrier(cnt, gen, ++bgen);
  }

  // ---- final classifier (jw==0 WG of each group) ----
  if (jw == 0) {
    const float* hfin = hbuf + ((Tlen-1)&1)*Bsz*Hn;
    int b = tid >> 3, cc = tid & 7;
    int bG = bG0 + b;
    const float4* hv = reinterpret_cast<const float4*>(hfin + (size_t)bG*Hn);
    const float4* wv = reinterpret_cast<const float4*>(Wfc + cc*Hn);
    float s0=0,s1=0,s2=0,s3=0;
    #pragma unroll 4
    for (int k = 0; k < Hn/4; ++k) {
      float4 a = hv[k], w = wv[k];
      s0 = fmaf(a.x,w.x,s0); s1 = fmaf(a.y,w.y,s1);
      s2 = fmaf(a.z,w.z,s2); s3 = fmaf(a.w,w.w,s3);
    }
    out[bG*Cn + cc] = (s0+s1)+(s2+s3) + bfc[cc];
  }
}

extern "C" void kernel_launch(void* const* d_in, const int* in_sizes, int n_in,
                              void* d_out, int out_size, void* d_ws, size_t ws_size,
                              hipStream_t stream) {
  const float* x    = (const float*)d_in[0];
  const float* mask = (const float*)d_in[1];
  const float* Wa   = (const float*)d_in[2];
  const float* ba   = (const float*)d_in[3];
  const float* Wih  = (const float*)d_in[4];
  const float* Whh  = (const float*)d_in[5];
  const float* bih  = (const float*)d_in[6];
  const float* bhh  = (const float*)d_in[7];
  const float* Wfc  = (const float*)d_in[8];
  const float* bfc  = (const float*)d_in[9];
  float* out = (float*)d_out;
  float* ws  = (float*)d_ws;

  // reset barrier counters + h/score buffers every launch (deterministic replay)
  hipMemsetAsync(d_ws, 0, (size_t)WS_FLOATS * sizeof(float), stream);

  (void)hipFuncSetAttribute((const void*)fused_att_lstm,
                            hipFuncAttributeMaxDynamicSharedMemorySize, LDS_BYTES);

  void* args[] = { (void*)&x, (void*)&mask, (void*)&Wa, (void*)&ba,
                   (void*)&Wih, (void*)&Whh, (void*)&bih, (void*)&bhh,
                   (void*)&Wfc, (void*)&bfc, (void*)&out, (void*)&ws };
  hipLaunchCooperativeKernel((void*)fused_att_lstm, dim3(NWG), dim3(TPB),
                             args, LDS_BYTES, stream);
}